// Round 12
// baseline (103.081 us; speedup 1.0000x reference)
//
#include <hip/hip_runtime.h>
#include <hip/hip_fp16.h>
#include <math.h>
#include <utility>

// AllPassMORR circulant conv2d via MFMA phase-GEMM. MI355X gfx950.
// x: [8,32,64,64] f32, weight: [8,36,8] f32, scale: [19] f32 -> out [8,64,64,64] f32
//
// out = NDK * sum_{qp<18} s_qp*(c1-c2)/(a*b),  a=C2-K2*cos(2pi*ph_q), b=..q+18
// ph_q[(pix),(p,t)] = sum_s xsq[pix, q*8+s] * |w|[p,q,(t-s)&7]/(2pi)
//   -> per q a [16 x 8] x [8 x 64] GEMM = MFMA 16x16x32 with K-octet 0 live,
//      B zeros in octets 1..3 (zero-tail loads), fp16 hi/lo split (3 MFMAs)
//      for ~fp32 phase accuracy (22-bit mantissa).
// R11: R5/R7/R9 all pinned ~42us = VALU-issue floor of the 604M-FMA conv.
// Offload conv to matrix pipe; VALU keeps only cos/rcp/acc.

typedef _Float16 f16x8 __attribute__((ext_vector_type(8)));
typedef float    f32x4 __attribute__((ext_vector_type(4)));
typedef unsigned int u32;
typedef u32 u32x4 __attribute__((ext_vector_type(4)));

template <class F, size_t... I>
__device__ __forceinline__ void sf_impl(F&& f, std::index_sequence<I...>) {
    (f(std::integral_constant<size_t, I>{}), ...);
}
template <size_t N, class F>
__device__ __forceinline__ void static_for(F&& f) {
    sf_impl(f, std::make_index_sequence<N>{});
}

__device__ __forceinline__ u32 pck(float a, float b) {
    _Float16 ha = (_Float16)a, hb = (_Float16)b;
    return (u32)__builtin_bit_cast(unsigned short, ha) |
           ((u32)__builtin_bit_cast(unsigned short, hb) << 16);
}

#define INV2PI 0.15915494309189535f

// ---- B-table prep: 288 slots of 68 u32 (272 B): slot = (q*4+pt)*2 + hl ----
// words [l*4+jp] l<16: f16 pair (w_rot(2jp) | w_rot(2jp+1)<<16); words 64..67 = 0
// w_rot(j) = |w[p, q, (t-j)&7]| * INV2PI, (p,t) = pt*16 + l  (p=flat>>3,t=flat&7)
__global__ void bprep(const float* __restrict__ wg, u32* __restrict__ bt) {
    int tid = blockIdx.x * 256 + threadIdx.x;
    int nthr = gridDim.x * 256;
    for (int e = tid; e < 288 * 68; e += nthr) {
        int slot = e / 68, wi = e - slot * 68;
        u32 val = 0u;
        if (wi < 64) {
            int hl = slot & 1, qpt = slot >> 1;
            int q = qpt >> 2, pt = qpt & 3;
            int l = wi >> 2, jp = wi & 3;
            int flat = pt * 16 + l, p = flat >> 3, t = flat & 7;
            float wa = fabsf(wg[(p * 36 + q) * 8 + ((t - 2 * jp) & 7)]) * INV2PI;
            float wb = fabsf(wg[(p * 36 + q) * 8 + ((t - 2 * jp - 1) & 7)]) * INV2PI;
            _Float16 ha = (_Float16)wa, hb = (_Float16)wb;
            if (hl == 0) {
                val = pck((float)ha, (float)hb);           // hi parts
            } else {
                val = pck(wa - (float)ha, wb - (float)hb); // lo parts
            }
        }
        bt[e] = val;
    }
}

__global__ __launch_bounds__(256, 4)
void morr_mfma(const float* __restrict__ xg, const u32* __restrict__ bt,
               const float* __restrict__ sg, float* __restrict__ out) {
    __shared__ union {
        u32   x[3200];       // 12.8 KB: x^2 tile packed (f16 hi | f16 lo<<16), [c][10][10]
        float o[64 * 65];    // 16.6 KB: output transpose
    } sm;

    constexpr double Ad = 0.987, Rd = 0.99;
    constexpr float K2  = (float)(2.0 * Ad * Rd);
    constexpr float C2  = (float)(1.0 + (Ad * Rd) * (Ad * Rd));
    constexpr float NDK = (float)(-(1.0 - Ad * Ad) * (1.0 - Rd * Rd) * (2.0 * Ad * Rd));

    const int tid = threadIdx.x;
    const int b   = blockIdx.z;
    const int gr0 = blockIdx.y * 8, gc0 = blockIdx.x * 8;

    // ---- stage x^2 tile as packed f16 hi/lo, 32ch x 10x10 halo ----
    for (int i = tid; i < 3200; i += 256) {
        int c = i / 100, rem = i - c * 100;
        int r = rem / 10, cl = rem - r * 10;
        int gr = gr0 - 1 + r, gc = gc0 - 1 + cl;
        float v = 0.f;
        if ((unsigned)gr < 64u && (unsigned)gc < 64u)
            v = xg[((b * 32 + c) * 64 + gr) * 64 + gc];
        v = v * v;                       // NOTE: 1/2pi lives in the w table
        _Float16 h = (_Float16)v;
        sm.x[i] = pck((float)h, v - (float)h);
    }
    __syncthreads();

    const int lane = tid & 63;
    const int wv   = tid >> 6;                 // wave = pixel-tile (16 px)
    const int c16  = lane & 15;
    const int pix  = wv * 16 + c16;            // A row = pixel (0..63 in block)
    const int abase = (pix >> 3) * 10 + (pix & 7);
    const int lnw  = (lane < 16) ? (lane << 2) : 64;   // B lane word-offset (zeros tail)

    float oacc[4][4];
    static_for<4>([&](auto P) { static_for<4>([&](auto R) { oacc[P][R] = 0.f; }); });

    #pragma unroll 1
    for (int qp = 0; qp < 18; ++qp) {
        const int q0 = qp, q1 = qp + 18;
        // ---- A fragments (hi/lo) for q0, q1: 8 taps each, bcast across octets ----
        u32 xw0[8], xw1[8];
        static_for<8>([&](auto J) {
            constexpr int j = J;
            const int ci0 = q0 * 8 + j, c0 = ci0 / 9, rm0 = ci0 - c0 * 9;
            const int ci1 = q1 * 8 + j, c1 = ci1 / 9, rm1 = ci1 - c1 * 9;
            xw0[j] = sm.x[abase + c0 * 100 + (rm0 / 3) * 10 + (rm0 - (rm0 / 3) * 3)];
            xw1[j] = sm.x[abase + c1 * 100 + (rm1 / 3) * 10 + (rm1 - (rm1 / 3) * 3)];
        });
        u32x4 a0h, a0l, a1h, a1l;
        static_for<4>([&](auto JP) {
            constexpr int jp = JP;
            a0h[jp] = (xw0[2 * jp] & 0xFFFFu) | (xw0[2 * jp + 1] << 16);
            a0l[jp] = (xw0[2 * jp] >> 16) | (xw0[2 * jp + 1] & 0xFFFF0000u);
            a1h[jp] = (xw1[2 * jp] & 0xFFFFu) | (xw1[2 * jp + 1] << 16);
            a1l[jp] = (xw1[2 * jp] >> 16) | (xw1[2 * jp + 1] & 0xFFFF0000u);
        });
        const f16x8 A0h = __builtin_bit_cast(f16x8, a0h);
        const f16x8 A0l = __builtin_bit_cast(f16x8, a0l);
        const f16x8 A1h = __builtin_bit_cast(f16x8, a1h);
        const f16x8 A1l = __builtin_bit_cast(f16x8, a1l);

        f32x4 ph0[4], ph1[4];
        static_for<4>([&](auto PT) {
            constexpr int pt = PT;
            const u32x4 b0h = *reinterpret_cast<const u32x4*>(bt + ((q0 * 4 + pt) * 2 + 0) * 68 + lnw);
            const u32x4 b0l = *reinterpret_cast<const u32x4*>(bt + ((q0 * 4 + pt) * 2 + 1) * 68 + lnw);
            const u32x4 b1h = *reinterpret_cast<const u32x4*>(bt + ((q1 * 4 + pt) * 2 + 0) * 68 + lnw);
            const u32x4 b1l = *reinterpret_cast<const u32x4*>(bt + ((q1 * 4 + pt) * 2 + 1) * 68 + lnw);
            f32x4 z = {0.f, 0.f, 0.f, 0.f};
            f32x4 acc0 = __builtin_amdgcn_mfma_f32_16x16x32_f16(A0l, __builtin_bit_cast(f16x8, b0h), z, 0, 0, 0);
            acc0 = __builtin_amdgcn_mfma_f32_16x16x32_f16(A0h, __builtin_bit_cast(f16x8, b0l), acc0, 0, 0, 0);
            acc0 = __builtin_amdgcn_mfma_f32_16x16x32_f16(A0h, __builtin_bit_cast(f16x8, b0h), acc0, 0, 0, 0);
            f32x4 acc1 = __builtin_amdgcn_mfma_f32_16x16x32_f16(A1l, __builtin_bit_cast(f16x8, b1h), z, 0, 0, 0);
            acc1 = __builtin_amdgcn_mfma_f32_16x16x32_f16(A1h, __builtin_bit_cast(f16x8, b1l), acc1, 0, 0, 0);
            acc1 = __builtin_amdgcn_mfma_f32_16x16x32_f16(A1h, __builtin_bit_cast(f16x8, b1h), acc1, 0, 0, 0);
            ph0[pt] = acc0;
            ph1[pt] = acc1;
        });

        // ---- nonlinearity + paired-rail accumulation ----
        const float sv = sg[qp];
        static_for<4>([&](auto PT) {
            constexpr int pt = PT;
            static_for<4>([&](auto R) {
                constexpr int r = R;
                float cA = __builtin_amdgcn_cosf(ph0[pt][r]);   // cos(2pi*rev)
                float cB = __builtin_amdgcn_cosf(ph1[pt][r]);
                float da = fmaf(-K2, cA, C2);
                float db = fmaf(-K2, cB, C2);
                float rr = __builtin_amdgcn_rcpf(da * db);
                oacc[pt][r] = fmaf(sv, (cA - cB) * rr, oacc[pt][r]);
            });
        });
    }

    // ---- transpose through LDS, then coalesced global write ----
    __syncthreads();     // all x-tile reads done (union reuse)
    static_for<4>([&](auto PT) {
        constexpr int pt = PT;
        static_for<4>([&](auto R) {
            constexpr int r = R;
            const int oc  = pt * 16 + c16;               // D col = (p*8+t)
            const int pxr = wv * 16 + (lane >> 4) * 4 + r;   // D row = pixel
            sm.o[oc * 65 + pxr] = NDK * oacc[pt][r];
        });
    });
    __syncthreads();
    for (int i = 0; i < 16; ++i) {
        int flat = i * 256 + tid;        // 0..4095
        int oc = flat >> 6, px = flat & 63;
        out[((b * 64 + oc) * 64 + gr0 + (px >> 3)) * 64 + gc0 + (px & 7)] = sm.o[oc * 65 + px];
    }
}

extern "C" void kernel_launch(void* const* d_in, const int* in_sizes, int n_in,
                              void* d_out, int out_size, void* d_ws, size_t ws_size,
                              hipStream_t stream) {
    const float* x = (const float*)d_in[0];
    const float* w = (const float*)d_in[1];
    const float* s = (const float*)d_in[2];
    float* outp = (float*)d_out;
    u32* bt = (u32*)d_ws;
    hipLaunchKernelGGL(bprep, dim3(32), dim3(256), 0, stream, w, bt);
    dim3 grid(8, 8, 8);
    hipLaunchKernelGGL(morr_mfma, grid, dim3(256), 0, stream, x, bt, s, outp);
}